// Round 1
// baseline (740.530 us; speedup 1.0000x reference)
//
#include <hip/hip_runtime.h>
#include <hip/hip_bf16.h>
#include <cstdint>
#include <cstddef>

// Problem constants
constexpr int HIDDEN = 2048;
constexpr int HEADS  = 16;
constexpr int HD     = 128;       // head dim
constexpr int BATCH  = 2;
constexpr int SEQ    = 2048;
constexpr int MROWS  = BATCH * SEQ;   // 4096 rows for all GEMMs

typedef __attribute__((ext_vector_type(8))) short bf16x8;
typedef __attribute__((ext_vector_type(4))) float f32x4;

__device__ __forceinline__ unsigned short f2bf(float f) {
  union { float f; unsigned int u; } c; c.f = f;
  unsigned int r = c.u + 0x7FFFu + ((c.u >> 16) & 1u);
  return (unsigned short)(r >> 16);
}
__device__ __forceinline__ float bf2f(unsigned short u) {
  union { unsigned int u; float f; } c; c.u = ((unsigned int)u) << 16;
  return c.f;
}

__device__ __forceinline__ void gload_lds16(const void* g, void* l) {
  __builtin_amdgcn_global_load_lds(
      (const __attribute__((address_space(1))) void*)g,
      (__attribute__((address_space(3))) void*)l, 16, 0, 0);
}

// ---------------- fp32 -> bf16 conversion (vectorized float4) ----------------
__global__ void k_cvt(const float* __restrict__ in, unsigned short* __restrict__ out, int n4) {
  int i = blockIdx.x * 256 + threadIdx.x;
  if (i >= n4) return;
  float4 v = reinterpret_cast<const float4*>(in)[i];
  ushort4 o;
  o.x = f2bf(v.x); o.y = f2bf(v.y); o.z = f2bf(v.z); o.w = f2bf(v.w);
  reinterpret_cast<ushort4*>(out)[i] = o;
}

// ---------------- NT GEMM: C[M,N] = A[M,K] * B[N,K]^T, bf16 in, fp32 acc ----
// MODE 0: write bf16 to [B,H,S,D]   (Q, K layout)
// MODE 1: write bf16 to [B,H,D,S]   (V transposed for PV fragment reads)
// MODE 2: write fp32 row-major [M,N] (final output)
template<int MODE>
__global__ __launch_bounds__(256, 2) void k_gemm(const unsigned short* __restrict__ A,
                                                 const unsigned short* __restrict__ Bm,
                                                 void* __restrict__ Cout,
                                                 int M, int N, int K) {
  __shared__ unsigned short As[128 * 32];
  __shared__ unsigned short Bs[128 * 32];
  const int t    = threadIdx.x;
  const int lane = t & 63;
  const int w    = t >> 6;
  const int wr   = w >> 1, wc = w & 1;
  const int m0   = blockIdx.y * 128;
  const int n0   = blockIdx.x * 128;
  const int l15  = lane & 15, lg = lane >> 4;

  f32x4 acc[4][4];
#pragma unroll
  for (int mi = 0; mi < 4; ++mi)
#pragma unroll
    for (int ni = 0; ni < 4; ++ni)
#pragma unroll
      for (int r = 0; r < 4; ++r) acc[mi][ni][r] = 0.f;

  const int rowA = t >> 2;          // 0..63
  const int col8 = (t & 3) * 8;
  const unsigned short* gA0 = A  + (size_t)(m0 + rowA) * K + col8;
  const unsigned short* gA1 = gA0 + (size_t)64 * K;
  const unsigned short* gB0 = Bm + (size_t)(n0 + rowA) * K + col8;
  const unsigned short* gB1 = gB0 + (size_t)64 * K;
  unsigned short* lA0 = As + t * 8;            // byte offset t*16 (linear per wave)
  unsigned short* lA1 = As + 64 * 32 + t * 8;
  unsigned short* lB0 = Bs + t * 8;
  unsigned short* lB1 = Bs + 64 * 32 + t * 8;

  for (int k0 = 0; k0 < K; k0 += 32) {
    gload_lds16(gA0 + k0, lA0);
    gload_lds16(gA1 + k0, lA1);
    gload_lds16(gB0 + k0, lB0);
    gload_lds16(gB1 + k0, lB1);
    __syncthreads();   // compiler emits vmcnt(0) drain before s_barrier

    bf16x8 a[4], b[4];
#pragma unroll
    for (int i = 0; i < 4; ++i)
      a[i] = *reinterpret_cast<const bf16x8*>(&As[(wr * 64 + i * 16 + l15) * 32 + lg * 8]);
#pragma unroll
    for (int i = 0; i < 4; ++i)
      b[i] = *reinterpret_cast<const bf16x8*>(&Bs[(wc * 64 + i * 16 + l15) * 32 + lg * 8]);
#pragma unroll
    for (int mi = 0; mi < 4; ++mi)
#pragma unroll
      for (int ni = 0; ni < 4; ++ni)
        acc[mi][ni] = __builtin_amdgcn_mfma_f32_16x16x32_bf16(a[mi], b[ni], acc[mi][ni], 0, 0, 0);
    __syncthreads();   // protect LDS from next iteration's staging
  }

  // Epilogue.  C/D layout: col = lane&15, row = (lane>>4)*4 + r  [m89-verified]
#pragma unroll
  for (int mi = 0; mi < 4; ++mi) {
#pragma unroll
    for (int ni = 0; ni < 4; ++ni) {
#pragma unroll
      for (int r = 0; r < 4; ++r) {
        int row = m0 + wr * 64 + mi * 16 + lg * 4 + r;   // m index (b*SEQ + s)
        int col = n0 + wc * 64 + ni * 16 + l15;          // n index (h*HD + d)
        float v = acc[mi][ni][r];
        if (MODE == 2) {
          reinterpret_cast<float*>(Cout)[(size_t)row * N + col] = v;
        } else {
          int b = row >> 11, s = row & (SEQ - 1);
          int h = col >> 7, d = col & (HD - 1);
          size_t addr;
          if (MODE == 0) addr = ((size_t)(b * HEADS + h) * SEQ + s) * HD + d;
          else           addr = ((size_t)(b * HEADS + h) * HD + d) * SEQ + s;
          reinterpret_cast<unsigned short*>(Cout)[addr] = f2bf(v);
        }
      }
    }
  }
}

// ---------------- RoPE on Q and K in [B,H,S,D] bf16 layout ----------------
// thread handles 8 (d, d+64) pairs for one (bh, s)
__global__ void k_rope(unsigned short* __restrict__ Qb, unsigned short* __restrict__ Kb) {
  int idx = blockIdx.x * 256 + threadIdx.x;  // 32 * 2048 * 8 = 524288 threads
  int c  = idx & 7;
  int s  = (idx >> 3) & (SEQ - 1);
  int bh = idx >> 14;
  size_t base = ((size_t)bh * SEQ + s) * HD + c * 8;

  bf16x8 ql = *reinterpret_cast<const bf16x8*>(Qb + base);
  bf16x8 qh = *reinterpret_cast<const bf16x8*>(Qb + base + 64);
  bf16x8 kl = *reinterpret_cast<const bf16x8*>(Kb + base);
  bf16x8 kh = *reinterpret_cast<const bf16x8*>(Kb + base + 64);
  bf16x8 qlo, qho, klo, kho;
#pragma unroll
  for (int j = 0; j < 8; ++j) {
    float d   = (float)(c * 8 + j);
    // inv_freq = 10000^(-d/64) = exp(-d * ln(10000)/64)
    float ang = (float)s * expf(d * -0.14391156511756683f);
    float sn, cs;
    __sincosf(ang, &sn, &cs);
    float a0 = bf2f((unsigned short)ql[j]), a1 = bf2f((unsigned short)qh[j]);
    qlo[j] = (short)f2bf(a0 * cs - a1 * sn);
    qho[j] = (short)f2bf(a1 * cs + a0 * sn);
    float b0 = bf2f((unsigned short)kl[j]), b1 = bf2f((unsigned short)kh[j]);
    klo[j] = (short)f2bf(b0 * cs - b1 * sn);
    kho[j] = (short)f2bf(b1 * cs + b0 * sn);
  }
  *reinterpret_cast<bf16x8*>(Qb + base)      = qlo;
  *reinterpret_cast<bf16x8*>(Qb + base + 64) = qho;
  *reinterpret_cast<bf16x8*>(Kb + base)      = klo;
  *reinterpret_cast<bf16x8*>(Kb + base + 64) = kho;
}

// ---------------- causal flash attention ----------------
// grid (SEQ/64, BATCH*HEADS), 256 threads = 4 waves, each wave owns 16 q-rows.
// Q,K in [B,H,S,D] bf16; V transposed [B,H,D,S] bf16; O out [B,S,HEADS*HD] bf16.
__global__ __launch_bounds__(256) void k_attn(const unsigned short* __restrict__ Q,
                                              const unsigned short* __restrict__ Kk,
                                              const unsigned short* __restrict__ Vt,
                                              unsigned short* __restrict__ O) {
  __shared__ unsigned short P_lds[4][16 * 32];
  const int t    = threadIdx.x;
  const int lane = t & 63;
  const int w    = t >> 6;
  const int bh   = blockIdx.y;
  const int b    = bh >> 4, h = bh & 15;
  const int q0   = blockIdx.x * 64 + w * 16;
  const int l15  = lane & 15, lg = lane >> 4;

  const unsigned short* Qb = Q  + (size_t)bh * SEQ * HD;
  const unsigned short* Kb = Kk + (size_t)bh * SEQ * HD;
  const unsigned short* Vb = Vt + (size_t)bh * HD * SEQ;

  // Q fragments hoisted (A-operand: row = lane&15, k = (lane>>4)*8+i)
  bf16x8 qf[4];
#pragma unroll
  for (int c = 0; c < 4; ++c)
    qf[c] = *reinterpret_cast<const bf16x8*>(Qb + (size_t)(q0 + l15) * HD + c * 32 + lg * 8);

  float mrow[4], lrow[4];
  f32x4 oacc[8];
#pragma unroll
  for (int r = 0; r < 4; ++r) { mrow[r] = -1e30f; lrow[r] = 0.f; }
#pragma unroll
  for (int dt = 0; dt < 8; ++dt)
#pragma unroll
    for (int r = 0; r < 4; ++r) oacc[dt][r] = 0.f;

  const int nb = (q0 + 16 + 31) >> 5;            // causal: kv blocks of 32
  const float scale = 0.08838834764831845f;      // 1/sqrt(128)

  for (int kb = 0; kb < nb; ++kb) {
    const int kv0 = kb * 32;
    f32x4 sc[2];
#pragma unroll
    for (int tt = 0; tt < 2; ++tt)
#pragma unroll
      for (int r = 0; r < 4; ++r) sc[tt][r] = 0.f;

#pragma unroll
    for (int tt = 0; tt < 2; ++tt)
#pragma unroll
      for (int c = 0; c < 4; ++c) {
        bf16x8 kf = *reinterpret_cast<const bf16x8*>(
            Kb + (size_t)(kv0 + tt * 16 + l15) * HD + c * 32 + lg * 8);
        sc[tt] = __builtin_amdgcn_mfma_f32_16x16x32_bf16(qf[c], kf, sc[tt], 0, 0, 0);
      }

    // scale + causal mask + online softmax.  D layout: row q = lg*4+r, col k = tt*16+l15
    float p[2][4], alpha[4];
#pragma unroll
    for (int r = 0; r < 4; ++r) {
      int qg  = q0 + lg * 4 + r;
      int k0g = kv0 + l15;
      float v0 = sc[0][r] * scale;
      float v1 = sc[1][r] * scale;
      if (k0g > qg)      v0 = -1e30f;
      if (k0g + 16 > qg) v1 = -1e30f;
      float pmr = fmaxf(v0, v1);
      pmr = fmaxf(pmr, __shfl_xor(pmr, 1));
      pmr = fmaxf(pmr, __shfl_xor(pmr, 2));
      pmr = fmaxf(pmr, __shfl_xor(pmr, 4));
      pmr = fmaxf(pmr, __shfl_xor(pmr, 8));
      float mn = fmaxf(mrow[r], pmr);
      alpha[r] = __expf(mrow[r] - mn);
      mrow[r] = mn;
      float p0 = __expf(v0 - mn);
      float p1 = __expf(v1 - mn);
      p[0][r] = p0; p[1][r] = p1;
      float ps = p0 + p1;
      ps += __shfl_xor(ps, 1);
      ps += __shfl_xor(ps, 2);
      ps += __shfl_xor(ps, 4);
      ps += __shfl_xor(ps, 8);
      lrow[r] = lrow[r] * alpha[r] + ps;
    }

    // P -> LDS (per-wave private region), read back as A-fragment (transpose)
#pragma unroll
    for (int tt = 0; tt < 2; ++tt)
#pragma unroll
      for (int r = 0; r < 4; ++r)
        P_lds[w][(lg * 4 + r) * 32 + tt * 16 + l15] = f2bf(p[tt][r]);
    asm volatile("s_waitcnt lgkmcnt(0)" ::: "memory");  // wave-lockstep: all writes visible
    bf16x8 pa = *reinterpret_cast<const bf16x8*>(&P_lds[w][l15 * 32 + lg * 8]);

#pragma unroll
    for (int dt = 0; dt < 8; ++dt)
#pragma unroll
      for (int r = 0; r < 4; ++r) oacc[dt][r] *= alpha[r];

    // PV: B-operand V[k][dv] read from Vt[dv][k] (contiguous along k)
#pragma unroll
    for (int dt = 0; dt < 8; ++dt) {
      bf16x8 vf = *reinterpret_cast<const bf16x8*>(
          Vb + (size_t)(dt * 16 + l15) * SEQ + kv0 + lg * 8);
      oacc[dt] = __builtin_amdgcn_mfma_f32_16x16x32_bf16(pa, vf, oacc[dt], 0, 0, 0);
    }
  }

  // epilogue: O[b, s, h*HD + dv]
#pragma unroll
  for (int dt = 0; dt < 8; ++dt) {
#pragma unroll
    for (int r = 0; r < 4; ++r) {
      int qg = q0 + lg * 4 + r;
      int dv = dt * 16 + l15;
      float v = oacc[dt][r] / lrow[r];
      O[((size_t)(b * SEQ + qg) * HEADS + h) * HD + dv] = f2bf(v);
    }
  }
}

// ---------------- launch ----------------
extern "C" void kernel_launch(void* const* d_in, const int* in_sizes, int n_in,
                              void* d_out, int out_size, void* d_ws, size_t ws_size,
                              hipStream_t stream) {
  (void)in_sizes; (void)n_in; (void)out_size; (void)ws_size;
  const float* x  = (const float*)d_in[0];
  const float* Wq = (const float*)d_in[1];
  const float* Wk = (const float*)d_in[2];
  const float* Wv = (const float*)d_in[3];
  const float* Wo = (const float*)d_in[4];
  float* out = (float*)d_out;

  // workspace layout (bf16 = ushort).  Total ≈ 112 MB.
  unsigned short* xb  = (unsigned short*)d_ws;
  unsigned short* wqb = xb  + (size_t)MROWS * HIDDEN;
  unsigned short* wkb = wqb + (size_t)HIDDEN * HIDDEN;
  unsigned short* wvb = wkb + (size_t)HIDDEN * HIDDEN;
  unsigned short* wob = wvb + (size_t)HIDDEN * HIDDEN;
  unsigned short* Qb  = wob + (size_t)HIDDEN * HIDDEN;
  unsigned short* Kb  = Qb  + (size_t)MROWS * HIDDEN;
  unsigned short* Vtb = Kb  + (size_t)MROWS * HIDDEN;
  unsigned short* Ob  = Vtb + (size_t)MROWS * HIDDEN;

  int n4x = MROWS * HIDDEN / 4;     // 2,097,152
  int n4w = HIDDEN * HIDDEN / 4;    // 1,048,576
  k_cvt<<<(n4x + 255) / 256, 256, 0, stream>>>(x,  xb,  n4x);
  k_cvt<<<(n4w + 255) / 256, 256, 0, stream>>>(Wq, wqb, n4w);
  k_cvt<<<(n4w + 255) / 256, 256, 0, stream>>>(Wk, wkb, n4w);
  k_cvt<<<(n4w + 255) / 256, 256, 0, stream>>>(Wv, wvb, n4w);
  k_cvt<<<(n4w + 255) / 256, 256, 0, stream>>>(Wo, wob, n4w);

  dim3 gg(HIDDEN / 128, MROWS / 128);   // (16, 32)
  k_gemm<0><<<gg, 256, 0, stream>>>(xb, wqb, Qb,  MROWS, HIDDEN, HIDDEN);
  k_gemm<0><<<gg, 256, 0, stream>>>(xb, wkb, Kb,  MROWS, HIDDEN, HIDDEN);
  k_gemm<1><<<gg, 256, 0, stream>>>(xb, wvb, Vtb, MROWS, HIDDEN, HIDDEN);

  k_rope<<<(BATCH * HEADS * SEQ * 8) / 256, 256, 0, stream>>>(Qb, Kb);

  k_attn<<<dim3(SEQ / 64, BATCH * HEADS), 256, 0, stream>>>(Qb, Kb, Vtb, Ob);

  k_gemm<2><<<gg, 256, 0, stream>>>(Ob, wob, out, MROWS, HIDDEN, HIDDEN);
}

// Round 2
// 508.652 us; speedup vs baseline: 1.4559x; 1.4559x over previous
//
#include <hip/hip_runtime.h>
#include <hip/hip_bf16.h>
#include <cstdint>
#include <cstddef>

// Problem constants
constexpr int HIDDEN = 2048;
constexpr int HEADS  = 16;
constexpr int HD     = 128;       // head dim
constexpr int BATCH  = 2;
constexpr int SEQ    = 2048;
constexpr int MROWS  = BATCH * SEQ;   // 4096 rows for all GEMMs

typedef __attribute__((ext_vector_type(8))) short bf16x8;
typedef __attribute__((ext_vector_type(4))) float f32x4;

__device__ __forceinline__ unsigned short f2bf(float f) {
  union { float f; unsigned int u; } c; c.f = f;
  unsigned int r = c.u + 0x7FFFu + ((c.u >> 16) & 1u);
  return (unsigned short)(r >> 16);
}
__device__ __forceinline__ float bf2f(unsigned short u) {
  union { unsigned int u; float f; } c; c.u = ((unsigned int)u) << 16;
  return c.f;
}

__device__ __forceinline__ void gload_lds16(const void* g, void* l) {
  __builtin_amdgcn_global_load_lds(
      (const __attribute__((address_space(1))) void*)g,
      (__attribute__((address_space(3))) void*)l, 16, 0, 0);
}

// ---------------- fp32 -> bf16 conversion (vectorized float4) ----------------
__global__ void k_cvt(const float* __restrict__ in, unsigned short* __restrict__ out, int n4) {
  int i = blockIdx.x * 256 + threadIdx.x;
  if (i >= n4) return;
  float4 v = reinterpret_cast<const float4*>(in)[i];
  ushort4 o;
  o.x = f2bf(v.x); o.y = f2bf(v.y); o.z = f2bf(v.z); o.w = f2bf(v.w);
  reinterpret_cast<ushort4*>(out)[i] = o;
}

// ---------------- NT GEMM: C[M,N] = A[M,K] * B[N,K]^T, bf16 in, fp32 acc ----
// MODE 0: write bf16 to [B,H,S,D]   (Q, K layout)
// MODE 1: write bf16 to [B,H,D,S]   (V transposed for PV fragment reads)
// MODE 2: write fp32 row-major [M,N] (final output)
template<int MODE>
__global__ __launch_bounds__(256, 2) void k_gemm(const unsigned short* __restrict__ A,
                                                 const unsigned short* __restrict__ Bm,
                                                 void* __restrict__ Cout,
                                                 int M, int N, int K) {
  __shared__ unsigned short As[128 * 32];
  __shared__ unsigned short Bs[128 * 32];
  const int t    = threadIdx.x;
  const int lane = t & 63;
  const int w    = t >> 6;
  const int wr   = w >> 1, wc = w & 1;
  const int m0   = blockIdx.y * 128;
  const int n0   = blockIdx.x * 128;
  const int l15  = lane & 15, lg = lane >> 4;

  f32x4 acc[4][4];
#pragma unroll
  for (int mi = 0; mi < 4; ++mi)
#pragma unroll
    for (int ni = 0; ni < 4; ++ni)
#pragma unroll
      for (int r = 0; r < 4; ++r) acc[mi][ni][r] = 0.f;

  const int rowA = t >> 2;          // 0..63
  const int col8 = (t & 3) * 8;
  const unsigned short* gA0 = A  + (size_t)(m0 + rowA) * K + col8;
  const unsigned short* gA1 = gA0 + (size_t)64 * K;
  const unsigned short* gB0 = Bm + (size_t)(n0 + rowA) * K + col8;
  const unsigned short* gB1 = gB0 + (size_t)64 * K;
  unsigned short* lA0 = As + t * 8;            // byte offset t*16 (linear per wave)
  unsigned short* lA1 = As + 64 * 32 + t * 8;
  unsigned short* lB0 = Bs + t * 8;
  unsigned short* lB1 = Bs + 64 * 32 + t * 8;

  for (int k0 = 0; k0 < K; k0 += 32) {
    gload_lds16(gA0 + k0, lA0);
    gload_lds16(gA1 + k0, lA1);
    gload_lds16(gB0 + k0, lB0);
    gload_lds16(gB1 + k0, lB1);
    __syncthreads();   // compiler emits vmcnt(0) drain before s_barrier

    bf16x8 a[4], b[4];
#pragma unroll
    for (int i = 0; i < 4; ++i)
      a[i] = *reinterpret_cast<const bf16x8*>(&As[(wr * 64 + i * 16 + l15) * 32 + lg * 8]);
#pragma unroll
    for (int i = 0; i < 4; ++i)
      b[i] = *reinterpret_cast<const bf16x8*>(&Bs[(wc * 64 + i * 16 + l15) * 32 + lg * 8]);
#pragma unroll
    for (int mi = 0; mi < 4; ++mi)
#pragma unroll
      for (int ni = 0; ni < 4; ++ni)
        acc[mi][ni] = __builtin_amdgcn_mfma_f32_16x16x32_bf16(a[mi], b[ni], acc[mi][ni], 0, 0, 0);
    __syncthreads();   // protect LDS from next iteration's staging
  }

  // Epilogue.  C/D layout: col = lane&15, row = (lane>>4)*4 + r  [m89-verified]
#pragma unroll
  for (int mi = 0; mi < 4; ++mi) {
#pragma unroll
    for (int ni = 0; ni < 4; ++ni) {
#pragma unroll
      for (int r = 0; r < 4; ++r) {
        int row = m0 + wr * 64 + mi * 16 + lg * 4 + r;   // m index (b*SEQ + s)
        int col = n0 + wc * 64 + ni * 16 + l15;          // n index (h*HD + d)
        float v = acc[mi][ni][r];
        if (MODE == 2) {
          reinterpret_cast<float*>(Cout)[(size_t)row * N + col] = v;
        } else {
          int b = row >> 11, s = row & (SEQ - 1);
          int h = col >> 7, d = col & (HD - 1);
          size_t addr;
          if (MODE == 0) addr = ((size_t)(b * HEADS + h) * SEQ + s) * HD + d;
          else           addr = ((size_t)(b * HEADS + h) * HD + d) * SEQ + s;
          reinterpret_cast<unsigned short*>(Cout)[addr] = f2bf(v);
        }
      }
    }
  }
}

// ---------------- RoPE on Q and K in [B,H,S,D] bf16 layout ----------------
// thread handles 8 (d, d+64) pairs for one (bh, s)
__global__ void k_rope(unsigned short* __restrict__ Qb, unsigned short* __restrict__ Kb) {
  int idx = blockIdx.x * 256 + threadIdx.x;  // 32 * 2048 * 8 = 524288 threads
  int c  = idx & 7;
  int s  = (idx >> 3) & (SEQ - 1);
  int bh = idx >> 14;
  size_t base = ((size_t)bh * SEQ + s) * HD + c * 8;

  bf16x8 ql = *reinterpret_cast<const bf16x8*>(Qb + base);
  bf16x8 qh = *reinterpret_cast<const bf16x8*>(Qb + base + 64);
  bf16x8 kl = *reinterpret_cast<const bf16x8*>(Kb + base);
  bf16x8 kh = *reinterpret_cast<const bf16x8*>(Kb + base + 64);
  bf16x8 qlo, qho, klo, kho;
#pragma unroll
  for (int j = 0; j < 8; ++j) {
    float d   = (float)(c * 8 + j);
    // inv_freq = 10000^(-d/64) = exp(-d * ln(10000)/64)
    float ang = (float)s * expf(d * -0.14391156511756683f);
    float sn, cs;
    __sincosf(ang, &sn, &cs);
    float a0 = bf2f((unsigned short)ql[j]), a1 = bf2f((unsigned short)qh[j]);
    qlo[j] = (short)f2bf(a0 * cs - a1 * sn);
    qho[j] = (short)f2bf(a1 * cs + a0 * sn);
    float b0 = bf2f((unsigned short)kl[j]), b1 = bf2f((unsigned short)kh[j]);
    klo[j] = (short)f2bf(b0 * cs - b1 * sn);
    kho[j] = (short)f2bf(b1 * cs + b0 * sn);
  }
  *reinterpret_cast<bf16x8*>(Qb + base)      = qlo;
  *reinterpret_cast<bf16x8*>(Qb + base + 64) = qho;
  *reinterpret_cast<bf16x8*>(Kb + base)      = klo;
  *reinterpret_cast<bf16x8*>(Kb + base + 64) = kho;
}

// ---------------- causal flash attention (v2) ----------------
// grid (SEQ/128, BATCH*HEADS), 512 threads = 8 waves, each wave owns 16 q-rows.
// K staged in LDS (XOR-swizzled, via pre-swizzled global source), KVBLK=64.
// V read direct from global in transposed [B,H,D,S] layout (L2-resident).
// Softmax: per-lane deferred row-sums + defer-max (THR=8).
constexpr int QB  = 128;   // q rows per block
constexpr int KVB = 64;    // kv rows per iteration

__global__ __launch_bounds__(512, 4) void k_attn(const unsigned short* __restrict__ Q,
                                                 const unsigned short* __restrict__ Kk,
                                                 const unsigned short* __restrict__ Vt,
                                                 unsigned short* __restrict__ O) {
  __shared__ char lds[16384 + 16384];   // K tile 64x128 bf16 (swz) + P 8x(16x64) bf16 (swz)
  char* Ks = lds;
  char* Ps = lds + 16384;

  const int t    = threadIdx.x;
  const int lane = t & 63;
  const int w    = t >> 6;
  const int l15  = lane & 15, lg = lane >> 4;
  const int bh   = blockIdx.y;
  const int b    = bh >> 4, h = bh & 15;
  const int q0b  = blockIdx.x * QB;
  const int q0w  = q0b + w * 16;
  const int qw_hi = q0w + 15;

  const unsigned short* Qb = Q  + (size_t)bh * SEQ * HD;
  const unsigned short* Kb = Kk + (size_t)bh * SEQ * HD;
  const unsigned short* Vb = Vt + (size_t)bh * HD * SEQ;

  // Q fragments hoisted (A-operand: row = lane&15 -> q, k = (lane>>4)*8+i -> d)
  bf16x8 qf[4];
#pragma unroll
  for (int c = 0; c < 4; ++c)
    qf[c] = *reinterpret_cast<const bf16x8*>(Qb + (size_t)(q0w + l15) * HD + c * 32 + lg * 8);

  float mrow[4], lpart[4];
  f32x4 oacc[8];
#pragma unroll
  for (int r = 0; r < 4; ++r) { mrow[r] = -1e30f; lpart[r] = 0.f; }
#pragma unroll
  for (int dt = 0; dt < 8; ++dt)
#pragma unroll
    for (int r = 0; r < 4; ++r) oacc[dt][r] = 0.f;

  // K staging addresses: LDS linear dest, inverse-swizzled global source (rule #21).
  // LDS byte p holds K[row = p>>8][byte (p&255) ^ ((row&7)<<4)]
  const int sp    = t * 16;
  const int srow  = sp >> 8;                            // 0..31 (second gload adds 32)
  const int scolb = (sp & 255) ^ ((srow & 7) << 4);
  const unsigned short* ksrc = Kb + (size_t)srow * HD + (scolb >> 1);
  char* kdst = Ks + sp;

  const float scale = 0.08838834764831845f;      // 1/sqrt(128)
  const int nb = q0b / KVB + 2;                  // covers kv <= q0b+127

  for (int kb = 0; kb < nb; ++kb) {
    const int kv0 = kb * KVB;
    gload_lds16(ksrc + (size_t)kv0 * HD, kdst);
    gload_lds16(ksrc + (size_t)(kv0 + 32) * HD, kdst + 8192);   // (row+32)&7 == row&7
    __syncthreads();

    if (kv0 <= qw_hi) {          // wave-uniform causal skip
      // ---- QK^T ----
      f32x4 sc[4];
#pragma unroll
      for (int tt = 0; tt < 4; ++tt)
#pragma unroll
        for (int r = 0; r < 4; ++r) sc[tt][r] = 0.f;
#pragma unroll
      for (int tt = 0; tt < 4; ++tt) {
        const int krow = tt * 16 + l15;
        const int xr   = (krow & 7) << 4;
#pragma unroll
        for (int c = 0; c < 4; ++c) {
          bf16x8 kf = *reinterpret_cast<const bf16x8*>(
              Ks + krow * 256 + ((c * 64 + lg * 16) ^ xr));
          sc[tt] = __builtin_amdgcn_mfma_f32_16x16x32_bf16(qf[c], kf, sc[tt], 0, 0, 0);
        }
      }

      // ---- online softmax (defer-max THR=8, per-lane deferred sums) ----
      const int prow_base = lg * 4;
      const int xp_base   = 0;  (void)xp_base;
#pragma unroll
      for (int r = 0; r < 4; ++r) {
        const int qg = q0w + lg * 4 + r;
        float v0 = sc[0][r] * scale, v1 = sc[1][r] * scale;
        float v2 = sc[2][r] * scale, v3 = sc[3][r] * scale;
        if (kv0 +      l15 > qg) v0 = -1e30f;
        if (kv0 + 16 + l15 > qg) v1 = -1e30f;
        if (kv0 + 32 + l15 > qg) v2 = -1e30f;
        if (kv0 + 48 + l15 > qg) v3 = -1e30f;
        float pm = fmaxf(fmaxf(v0, v1), fmaxf(v2, v3));
        pm = fmaxf(pm, __shfl_xor(pm, 1));
        pm = fmaxf(pm, __shfl_xor(pm, 2));
        pm = fmaxf(pm, __shfl_xor(pm, 4));
        pm = fmaxf(pm, __shfl_xor(pm, 8));
        if (__any(pm > mrow[r] + 8.f)) {           // T13 defer-max
          float mn = fmaxf(mrow[r], pm);
          float al = __expf(mrow[r] - mn);
          lpart[r] *= al;
#pragma unroll
          for (int dt = 0; dt < 8; ++dt) oacc[dt][r] *= al;
          mrow[r] = mn;
        }
        float p0 = __expf(v0 - mrow[r]);
        float p1 = __expf(v1 - mrow[r]);
        float p2 = __expf(v2 - mrow[r]);
        float p3 = __expf(v3 - mrow[r]);
        lpart[r] += (p0 + p1) + (p2 + p3);
        // P -> LDS, swizzled (row stride 128B, XOR (row&7)<<4)
        const int prow = prow_base + r;
        const int xpr  = (prow & 7) << 4;
        char* pw = Ps + w * 2048 + prow * 128;
        *reinterpret_cast<unsigned short*>(pw + (((0 * 32) + l15 * 2) ^ xpr)) = f2bf(p0);
        *reinterpret_cast<unsigned short*>(pw + (((1 * 32) + l15 * 2) ^ xpr)) = f2bf(p1);
        *reinterpret_cast<unsigned short*>(pw + (((2 * 32) + l15 * 2) ^ xpr)) = f2bf(p2);
        *reinterpret_cast<unsigned short*>(pw + (((3 * 32) + l15 * 2) ^ xpr)) = f2bf(p3);
      }
      asm volatile("s_waitcnt lgkmcnt(0)" ::: "memory");  // wave-local P visibility

      // ---- PV ----
      const int xq = (l15 & 7) << 4;
      const char* pr = Ps + w * 2048 + l15 * 128;
      bf16x8 pa0 = *reinterpret_cast<const bf16x8*>(pr + ((0  + lg * 16) ^ xq));
      bf16x8 pa1 = *reinterpret_cast<const bf16x8*>(pr + ((64 + lg * 16) ^ xq));
#pragma unroll
      for (int dt = 0; dt < 8; ++dt) {
        const unsigned short* vrow = Vb + (size_t)(dt * 16 + l15) * SEQ + kv0 + lg * 8;
        bf16x8 vf0 = *reinterpret_cast<const bf16x8*>(vrow);
        bf16x8 vf1 = *reinterpret_cast<const bf16x8*>(vrow + 32);
        oacc[dt] = __builtin_amdgcn_mfma_f32_16x16x32_bf16(pa0, vf0, oacc[dt], 0, 0, 0);
        oacc[dt] = __builtin_amdgcn_mfma_f32_16x16x32_bf16(pa1, vf1, oacc[dt], 0, 0, 0);
      }
    }
    __syncthreads();
  }

  // ---- epilogue: reduce deferred sums across the 16 lanes of each row ----
  float inv[4];
#pragma unroll
  for (int r = 0; r < 4; ++r) {
    float ls = lpart[r];
    ls += __shfl_xor(ls, 1);
    ls += __shfl_xor(ls, 2);
    ls += __shfl_xor(ls, 4);
    ls += __shfl_xor(ls, 8);
    inv[r] = 1.0f / ls;
  }
#pragma unroll
  for (int dt = 0; dt < 8; ++dt) {
#pragma unroll
    for (int r = 0; r < 4; ++r) {
      int qg = q0w + lg * 4 + r;
      int dv = dt * 16 + l15;
      O[((size_t)(b * SEQ + qg) * HEADS + h) * HD + dv] = f2bf(oacc[dt][r] * inv[r]);
    }
  }
}

// ---------------- launch ----------------
extern "C" void kernel_launch(void* const* d_in, const int* in_sizes, int n_in,
                              void* d_out, int out_size, void* d_ws, size_t ws_size,
                              hipStream_t stream) {
  (void)in_sizes; (void)n_in; (void)out_size; (void)ws_size;
  const float* x  = (const float*)d_in[0];
  const float* Wq = (const float*)d_in[1];
  const float* Wk = (const float*)d_in[2];
  const float* Wv = (const float*)d_in[3];
  const float* Wo = (const float*)d_in[4];
  float* out = (float*)d_out;

  // workspace layout (bf16 = ushort).  Total ≈ 112 MB.
  unsigned short* xb  = (unsigned short*)d_ws;
  unsigned short* wqb = xb  + (size_t)MROWS * HIDDEN;
  unsigned short* wkb = wqb + (size_t)HIDDEN * HIDDEN;
  unsigned short* wvb = wkb + (size_t)HIDDEN * HIDDEN;
  unsigned short* wob = wvb + (size_t)HIDDEN * HIDDEN;
  unsigned short* Qb  = wob + (size_t)HIDDEN * HIDDEN;
  unsigned short* Kb  = Qb  + (size_t)MROWS * HIDDEN;
  unsigned short* Vtb = Kb  + (size_t)MROWS * HIDDEN;
  unsigned short* Ob  = Vtb + (size_t)MROWS * HIDDEN;

  int n4x = MROWS * HIDDEN / 4;     // 2,097,152
  int n4w = HIDDEN * HIDDEN / 4;    // 1,048,576
  k_cvt<<<(n4x + 255) / 256, 256, 0, stream>>>(x,  xb,  n4x);
  k_cvt<<<(n4w + 255) / 256, 256, 0, stream>>>(Wq, wqb, n4w);
  k_cvt<<<(n4w + 255) / 256, 256, 0, stream>>>(Wk, wkb, n4w);
  k_cvt<<<(n4w + 255) / 256, 256, 0, stream>>>(Wv, wvb, n4w);
  k_cvt<<<(n4w + 255) / 256, 256, 0, stream>>>(Wo, wob, n4w);

  dim3 gg(HIDDEN / 128, MROWS / 128);   // (16, 32)
  k_gemm<0><<<gg, 256, 0, stream>>>(xb, wqb, Qb,  MROWS, HIDDEN, HIDDEN);
  k_gemm<0><<<gg, 256, 0, stream>>>(xb, wkb, Kb,  MROWS, HIDDEN, HIDDEN);
  k_gemm<1><<<gg, 256, 0, stream>>>(xb, wvb, Vtb, MROWS, HIDDEN, HIDDEN);

  k_rope<<<(BATCH * HEADS * SEQ * 8) / 256, 256, 0, stream>>>(Qb, Kb);

  k_attn<<<dim3(SEQ / QB, BATCH * HEADS), 512, 0, stream>>>(Qb, Kb, Vtb, Ob);

  k_gemm<2><<<gg, 256, 0, stream>>>(Ob, wob, out, MROWS, HIDDEN, HIDDEN);
}